// Round 1
// baseline (1191.237 us; speedup 1.0000x reference)
//
#include <hip/hip_runtime.h>
#include <math.h>

// Problem constants (fixed by setup_inputs)
static constexpr int BATCH = 32;
static constexpr int NPRED = 512;   // outputs rows (LAP columns)
static constexpr int NTGT  = 200;   // targets rows (LAP rows)
static constexpr int DIM   = 768;
#define BIGF 1e9f

// ---------------------------------------------------------------------------
// Row squared-norms: one wave per row, 768 floats = 192 float4 = 64 lanes x 3
// ---------------------------------------------------------------------------
__global__ __launch_bounds__(64) void row_norms_kernel(const float* __restrict__ x,
                                                       float* __restrict__ out) {
    int row = blockIdx.x;
    const float4* r = (const float4*)(x + (size_t)row * DIM);
    float s = 0.f;
#pragma unroll
    for (int k = 0; k < 3; ++k) {
        float4 v = r[threadIdx.x + 64 * k];
        s += v.x * v.x + v.y * v.y + v.z * v.z + v.w * v.w;
    }
#pragma unroll
    for (int off = 32; off; off >>= 1) s += __shfl_down(s, off);
    if (threadIdx.x == 0) out[row] = s;
}

// ---------------------------------------------------------------------------
// cost[b][m][n] = sqrt(max(nt[m] + no[n] - 2 * dot(T[m], O[n]), 0))
// Tiled fp32 GEMM: 32(m) x 64(n) tile, BK=32, 256 threads, 2x4 acc/thread.
// ---------------------------------------------------------------------------
__global__ __launch_bounds__(256) void cost_kernel(const float* __restrict__ O,
                                                   const float* __restrict__ T,
                                                   const float* __restrict__ no_arr,
                                                   const float* __restrict__ nt_arr,
                                                   float* __restrict__ cost) {
    const int b  = blockIdx.z;
    const int m0 = blockIdx.y * 32;
    const int n0 = blockIdx.x * 64;
    const float* Tb = T + (size_t)b * NTGT * DIM;
    const float* Ob = O + (size_t)b * NPRED * DIM;

    __shared__ float As[32][33];  // [k][m], +1 pad
    __shared__ float Bs[32][65];  // [k][n], +1 pad

    const int tid = threadIdx.x;
    const int tx = tid & 15;   // n
    const int ty = tid >> 4;   // m

    float acc[2][4] = {{0.f, 0.f, 0.f, 0.f}, {0.f, 0.f, 0.f, 0.f}};

    for (int k0 = 0; k0 < DIM; k0 += 32) {
        // A tile: 32 rows x 32 k = 256 float4, one per thread (clamped rows)
        {
            int ar = tid >> 3;
            int ak = (tid & 7) << 2;
            int gm = m0 + ar; if (gm > NTGT - 1) gm = NTGT - 1;
            float4 vA = *(const float4*)(Tb + (size_t)gm * DIM + k0 + ak);
            As[ak + 0][ar] = vA.x; As[ak + 1][ar] = vA.y;
            As[ak + 2][ar] = vA.z; As[ak + 3][ar] = vA.w;
        }
        // B tile: 64 rows x 32 k = 512 float4, two per thread
#pragma unroll
        for (int q = 0; q < 2; ++q) {
            int idx = tid * 2 + q;
            int br = idx >> 3;
            int bk = (idx & 7) << 2;
            float4 vB = *(const float4*)(Ob + (size_t)(n0 + br) * DIM + k0 + bk);
            Bs[bk + 0][br] = vB.x; Bs[bk + 1][br] = vB.y;
            Bs[bk + 2][br] = vB.z; Bs[bk + 3][br] = vB.w;
        }
        __syncthreads();
#pragma unroll
        for (int k = 0; k < 32; ++k) {
            float a0 = As[k][ty], a1 = As[k][ty + 16];
            float b0 = Bs[k][tx],      b1 = Bs[k][tx + 16];
            float b2 = Bs[k][tx + 32], b3 = Bs[k][tx + 48];
            acc[0][0] += a0 * b0; acc[0][1] += a0 * b1;
            acc[0][2] += a0 * b2; acc[0][3] += a0 * b3;
            acc[1][0] += a1 * b0; acc[1][1] += a1 * b1;
            acc[1][2] += a1 * b2; acc[1][3] += a1 * b3;
        }
        __syncthreads();
    }

#pragma unroll
    for (int i = 0; i < 2; ++i) {
        int gm = m0 + ty + 16 * i;
        if (gm < NTGT) {
            float ntv = nt_arr[b * NTGT + gm];
#pragma unroll
            for (int j = 0; j < 4; ++j) {
                int gn = n0 + tx + 16 * j;
                float d2 = ntv + no_arr[b * NPRED + gn] - 2.0f * acc[i][j];
                cost[((size_t)b * NTGT + gm) * NPRED + gn] = sqrtf(fmaxf(d2, 0.0f));
            }
        }
    }
}

// ---------------------------------------------------------------------------
// Jonker-Volgenant LAP, one block (512 threads) per batch.
// Rows = targets (1..200), cols = preds (1..512), thread tid owns col tid+1.
// Per-column state (v, minv, used) lives in registers; u/p/way in LDS.
// Argmin tie-break: lowest column index (matches jnp.argmin).
// ---------------------------------------------------------------------------
__global__ __launch_bounds__(512) void lap_kernel(const float* __restrict__ cost,
                                                  int* __restrict__ out) {
    const int b = blockIdx.x;
    const int tid = threadIdx.x;
    const float* C = cost + (size_t)b * NTGT * NPRED;  // [NTGT][NPRED]

    __shared__ float u_lds[NTGT + 1];
    __shared__ int   p_lds[NPRED + 1];
    __shared__ int   way_lds[NPRED];
    __shared__ float wv[8];
    __shared__ int   wi[8];
    __shared__ float s_delta;
    __shared__ int   s_j1;
    __shared__ int   g2p[NTGT];

    for (int k = tid; k < NTGT + 1; k += 512) u_lds[k] = 0.f;
    for (int k = tid; k < NPRED + 1; k += 512) p_lds[k] = 0;
    float v = 0.f;  // col dual for col tid+1
    __syncthreads();

    for (int i = 1; i <= NTGT; ++i) {
        if (tid == 0) p_lds[0] = i;
        float minv = BIGF;
        int used = 0;
        way_lds[tid] = 0;
        __syncthreads();

        int j0 = 0;
        int j1 = 0;
        for (int it = 0; it < NPRED + 1; ++it) {
            int i0 = p_lds[j0];           // uniform
            if (tid == j0 - 1) used = 1;  // mark current col used (j0>=1)
            float u_i0 = u_lds[i0];
            if (!used) {
                float cur = C[(size_t)(i0 - 1) * NPRED + tid] - u_i0 - v;
                if (cur < minv) { minv = cur; way_lds[tid] = j0; }
            }
            float masked = used ? BIGF : minv;

            // block argmin with first-index tie-break
            float bv = masked; int bi = tid;
#pragma unroll
            for (int off = 32; off; off >>= 1) {
                float ov = __shfl_down(bv, off);
                int   oi = __shfl_down(bi, off);
                if (ov < bv || (ov == bv && oi < bi)) { bv = ov; bi = oi; }
            }
            if ((tid & 63) == 0) { wv[tid >> 6] = bv; wi[tid >> 6] = bi; }
            __syncthreads();
            if (tid == 0) {
                float best = wv[0]; int besti = wi[0];
#pragma unroll
                for (int w = 1; w < 8; ++w) {
                    if (wv[w] < best) { best = wv[w]; besti = wi[w]; }
                }
                s_delta = best; s_j1 = besti + 1;
            }
            __syncthreads();
            float delta = s_delta;
            j1 = s_j1;
            int done = (p_lds[j1] == 0);

            // dual updates (reference: updates applied before termination test)
            if (used) {
                v -= delta;
                int pr = p_lds[tid + 1];
                u_lds[pr] += delta;  // distinct rows per used col: race-free
            } else {
                minv -= delta;
            }
            if (tid == 0) u_lds[p_lds[0]] += delta;  // virtual col 0 -> row i
            __syncthreads();
            if (done) break;
            j0 = j1;
        }

        // backtrack augmenting path (sequential, short)
        if (tid == 0) {
            int j = j1;
            while (j != 0) {
                int w = way_lds[j - 1];
                p_lds[j] = p_lds[w];
                j = w;
            }
        }
        __syncthreads();
    }

    // invert matching: g2p[row] = col (0-based pred index)
    {
        int r = p_lds[tid + 1];
        if (r > 0) g2p[r - 1] = tid;
    }
    __syncthreads();

    // sort by pred index via rank counting (values distinct)
    if (tid < NTGT) {
        int myv = g2p[tid];
        int rank = 0;
        for (int l = 0; l < NTGT; ++l) rank += (g2p[l] < myv) ? 1 : 0;
        out[b * 2 * NTGT + rank] = myv;          // index_i: sorted pred indices
        out[b * 2 * NTGT + NTGT + rank] = tid;   // index_j: gt index (argsort)
    }
}

extern "C" void kernel_launch(void* const* d_in, const int* in_sizes, int n_in,
                              void* d_out, int out_size, void* d_ws, size_t ws_size,
                              hipStream_t stream) {
    const float* outputs = (const float*)d_in[0];  // [32, 512, 768]
    const float* targets = (const float*)d_in[1];  // [32, 200, 768]
    int* out = (int*)d_out;                        // [32, 2, 200] int32

    float* cost   = (float*)d_ws;                         // [32][200][512]
    float* no_arr = cost + (size_t)BATCH * NTGT * NPRED;  // [32*512]
    float* nt_arr = no_arr + (size_t)BATCH * NPRED;       // [32*200]

    row_norms_kernel<<<BATCH * NPRED, 64, 0, stream>>>(outputs, no_arr);
    row_norms_kernel<<<BATCH * NTGT, 64, 0, stream>>>(targets, nt_arr);
    cost_kernel<<<dim3(NPRED / 64, (NTGT + 31) / 32, BATCH), 256, 0, stream>>>(
        outputs, targets, no_arr, nt_arr, cost);
    lap_kernel<<<BATCH, 512, 0, stream>>>(cost, out);
}